// Round 10
// baseline (9574.091 us; speedup 1.0000x reference)
//
#include <hip/hip_runtime.h>

#define IN_F 128
#define HID_F 64
#define OUT_F 32
#define ENC_NEG_INF 0x007FFFFFu
#define LOG2E 1.44269504088896340736f

typedef float f32x2 __attribute__((ext_vector_type(2)));

// packed dual-FMA (proven r8): acc.lo += w.lo*h.lo, acc.hi += w.hi*h.lo  (broadcast lo)
#define PK_LO(acc, w, hs) \
  asm("v_pk_fma_f32 %0, %1, %2, %0 op_sel_hi:[1,0,1]" : "+v"(acc) : "v"(w), "v"(hs))
// acc.lo += w.lo*h.hi, acc.hi += w.hi*h.hi  (broadcast hi)
#define PK_HI(acc, w, hs) \
  asm("v_pk_fma_f32 %0, %1, %2, %0 op_sel:[0,1,0]" : "+v"(acc) : "v"(w), "v"(hs))

// ---------------- workspace layout (float offsets) ----------------
#define OFF_OUT1   0
#define OFF_OUT2   1280000
#define OFF_D1     1920000
#define OFF_D2     1940000
#define OFF_SUM    1960000
#define ZERO_FLOATS 1960064
#define OFF_M1     1960064
#define OFF_M2     1980064
#define OFF_H1     2000064
#define OFF_H2     3280064
#define OFF_ES1    3920064
#define OFF_ED1    3940064
#define OFF_ES2    3960064
#define OFF_ED2    3980064
#define OFF_EBUF   4000064
#define OFF_ZX     4660064    // 20000*128 + 1024 pad  LSTM input projection (PACKED+SCALED)

__device__ __forceinline__ unsigned enc_f(float f) {
  unsigned b = __float_as_uint(f);
  return (b & 0x80000000u) ? ~b : (b | 0x80000000u);
}
__device__ __forceinline__ float dec_f(unsigned u) {
  unsigned b = (u & 0x80000000u) ? (u & 0x7FFFFFFFu) : ~u;
  return __uint_as_float(b);
}

// DPP quad_perm cross-lane (pure VALU): 0xB1 = swap within lane pairs (xor1)
template <int CTRL>
__device__ __forceinline__ float qperm(float x) {
  return __uint_as_float((unsigned)__builtin_amdgcn_update_dpp(
      0, (int)__float_as_uint(x), CTRL, 0xF, 0xF, true));
}

__global__ void k_initm(unsigned* __restrict__ m1, unsigned* __restrict__ m2, int n) {
  int i = blockIdx.x * blockDim.x + threadIdx.x;
  if (i < n) { m1[i] = ENC_NEG_INF; m2[i] = ENC_NEG_INF; }
}

// h1 = x @ W1 ; es1 = h1 . a_src ; ed1 = h1 . a_dst   (one wave per node)
__global__ void k_gemm1(const float* __restrict__ x, const float* __restrict__ W1,
                        const float* __restrict__ a_src, const float* __restrict__ a_dst,
                        float* __restrict__ h1, float* __restrict__ es, float* __restrict__ ed) {
  int n = blockIdx.x;
  int f = threadIdx.x;           // 0..63
  const float* xr = x + n * IN_F;
  float acc = 0.f;
#pragma unroll 8
  for (int k = 0; k < IN_F; ++k) acc = fmaf(xr[k], W1[k * HID_F + f], acc);
  h1[n * HID_F + f] = acc;
  float s = acc * a_src[f];
  float d = acc * a_dst[f];
#pragma unroll
  for (int off = 32; off; off >>= 1) {
    s += __shfl_down(s, off, 64);
    d += __shfl_down(d, off, 64);
  }
  if (f == 0) { es[n] = s; ed[n] = d; }
}

__global__ void k_emax(const int* __restrict__ ei, const float* __restrict__ es,
                       const float* __restrict__ ed, float* __restrict__ ebuf,
                       unsigned* __restrict__ menc, int E, int EP) {
  int i = blockIdx.x * blockDim.x + threadIdx.x;
  if (i >= EP) return;
  int src, dst;
  if (i < E) { src = ei[i]; dst = ei[E + i]; } else { src = dst = i - E; }
  float e = es[src] + ed[dst];
  e = (e >= 0.f) ? e : 0.2f * e;
  ebuf[i] = e;
  atomicMax(&menc[dst], enc_f(e));
}

__global__ void k_ep(const int* __restrict__ ei, float* __restrict__ ebuf,
                     const unsigned* __restrict__ menc, float* __restrict__ denom,
                     int E, int EP) {
  int i = blockIdx.x * blockDim.x + threadIdx.x;
  if (i >= EP) return;
  int dst = (i < E) ? ei[E + i] : (i - E);
  float p = __expf(ebuf[i] - dec_f(menc[dst]));
  ebuf[i] = p;
  atomicAdd(&denom[dst], p);
}

template <int F>
__global__ void k_aggr(const int* __restrict__ ei, const float* __restrict__ ebuf,
                       const float* __restrict__ denom, const float* __restrict__ h,
                       float* __restrict__ out, int E, int EP) {
  int gt = blockIdx.x * blockDim.x + threadIdx.x;
  int lane = gt % F;
  int e = gt / F;
  if (e >= EP) return;
  int src, dst;
  if (e < E) { src = ei[e]; dst = ei[E + e]; } else { src = dst = e - E; }
  float alpha = ebuf[e] / denom[dst];
  atomicAdd(&out[dst * F + lane], alpha * h[src * F + lane]);
}

__global__ void k_gemm2(const float* __restrict__ out1, const float* __restrict__ b1,
                        const float* __restrict__ W2, const float* __restrict__ a_src,
                        const float* __restrict__ a_dst, float* __restrict__ h2,
                        float* __restrict__ es, float* __restrict__ ed, int N) {
  int lane = threadIdx.x;
  int f = lane & 31;
  int n = blockIdx.x * 2 + (lane >> 5);
  if (n >= N) return;
  const float* r = out1 + n * HID_F;
  float acc = 0.f;
#pragma unroll 8
  for (int k = 0; k < HID_F; ++k) {
    float v = r[k] + b1[k];
    v = v > 0.f ? v : 0.f;
    acc = fmaf(v, W2[k * OUT_F + f], acc);
  }
  h2[n * OUT_F + f] = acc;
  float s = acc * a_src[f];
  float d = acc * a_dst[f];
#pragma unroll
  for (int off = 16; off; off >>= 1) {
    s += __shfl_down(s, off, 32);
    d += __shfl_down(d, off, 32);
  }
  if (f == 0) { es[n] = s; ed[n] = d; }
}

// Zx packed+scaled for round-9 LSTM layout: row r (gate-major: i,f,g,o) ->
//   pos = (r&31)*4 + (r>>5)    (unit-major, gate minor)
// LSTM lane 2j   reads float2 (zx_i, zx_f) at t*128 + j*4
// LSTM lane 2j+1 reads float2 (zx_g, zx_o) at t*128 + j*4 + 2
// rows i,f,o premultiplied by log2(e); row g by 2*log2(e)
__global__ void k_zx(const float* __restrict__ out2, const float* __restrict__ b2,
                     const float* __restrict__ Wih, const float* __restrict__ bih,
                     const float* __restrict__ bhh, float* __restrict__ Zx) {
  int r = threadIdx.x;   // 0..127
  int t = blockIdx.x;
  const float* xr = out2 + t * OUT_F;
  float acc = bih[r] + bhh[r];
#pragma unroll
  for (int k = 0; k < OUT_F; ++k) acc = fmaf(xr[k] + b2[k], Wih[r * OUT_F + k], acc);
  float scl = (r >= 64 && r < 96) ? 2.f * LOG2E : LOG2E;   // g-rows get 2L
  int pos = ((r & 31) << 2) | (r >> 5);
  Zx[t * 128 + pos] = acc * scl;
}

__global__ void k_mean(const float* __restrict__ out2, const float* __restrict__ b2,
                       float* __restrict__ sum, int N) {
  int k = threadIdx.x & 31;
  int row = threadIdx.x >> 5;   // 0..7
  float acc = 0.f;
  for (int n = blockIdx.x * 8 + row; n < N; n += gridDim.x * 8)
    acc += out2[n * OUT_F + k] + b2[k];
  __shared__ float s[256];
  s[threadIdx.x] = acc;
  __syncthreads();
  if (threadIdx.x < 32) {
    float tot = 0.f;
#pragma unroll
    for (int j = 0; j < 8; ++j) tot += s[j * 32 + k];
    atomicAdd(&sum[k], tot);
  }
}

__global__ void k_head(const float* __restrict__ sum, const float* __restrict__ w1,
                       const float* __restrict__ bb1, const float* __restrict__ w2,
                       const float* __restrict__ bb2, float* __restrict__ out, float invN) {
  if (threadIdx.x == 0 && blockIdx.x == 0) {
    float xc[32];
#pragma unroll
    for (int k = 0; k < 32; ++k) xc[k] = sum[k] * invN;
    float t2 = bb2[0];
    for (int j = 0; j < 16; ++j) {
      float a = bb1[j];
#pragma unroll
      for (int k = 0; k < 32; ++k) a = fmaf(w1[j * 32 + k], xc[k], a);
      a = a > 0.f ? a : 0.f;
      t2 = fmaf(w2[j], a, t2);
    }
    out[0] = 1.f / (1.f + __expf(-t2));
  }
}

// sequential LSTM round-9: ONE wave, zero barriers, zero LDS memory.
// Lane pair (2j, 2j+1) jointly computes ALL FOUR gate rows of unit j, k-split:
//   even lane sums k in [0,16), odd lane k in [16,32).
// Broadcast: 16 ds_bpermute (no ds_write leg!) with per-lane addr p*128 + k*8
//   (reads h_{16p+k} from even lane 32p+2k). Results packed into 8 f32x2 pairs
//   feeding 32 v_pk_fma (accP = (zi,zf) chain, accQ = (zg,zo) chain).
// Combine: 4 DPP xor-1 + 4 adds -> every lane holds all 4 z's (a+b commutes
//   bitwise, so even/odd get identical sums). Full gate tail in all lanes ->
//   h valid everywhere, no post-sigmoid exchange. 5 exp2 + 5 rcp.
__global__ void __launch_bounds__(64, 1) k_lstm(
    const float* __restrict__ Zx, const float* __restrict__ Whh,
    const float* __restrict__ fc1w, const float* __restrict__ fc1b,
    float* __restrict__ out, int N) {
  const int l = threadIdx.x;     // 0..63
  const int j = l >> 1;
  const int p = l & 1;
  const int rI = 0 * 32 + j, rF = 1 * 32 + j, rG = 2 * 32 + j, rO = 3 * 32 + j;

  // per-lane weights for its k-half, packed (row-pair) per k
  f32x2 wP[16], wQ[16];
#pragma unroll
  for (int k = 0; k < 16; ++k) {
    int kk = p * 16 + k;
    f32x2 a, b;
    a.x = Whh[rI * 32 + kk] * LOG2E;
    a.y = Whh[rF * 32 + kk] * LOG2E;
    b.x = Whh[rG * 32 + kk] * (2.f * LOG2E);
    b.y = Whh[rO * 32 + kk] * LOG2E;
    wP[k] = a; wQ[k] = b;
  }

  // bpermute byte addresses: h_{16p+k} lives in lane 32p+2k
  int ba[16];
#pragma unroll
  for (int k = 0; k < 16; ++k) ba[k] = p * 128 + k * 8;

  const float2* pz = (const float2*)Zx + l;   // lane's float2 column; step stride 64
  f32x2 zr[8];
#pragma unroll
  for (int s = 0; s < 8; ++s) { float2 v = pz[s * 64]; zr[s].x = v.x; zr[s].y = v.y; }

  const float n2L = -2.f * LOG2E;
  float h = 0.f, c = 0.f;
  // N divisible by 8 (N=20000)
  for (int t = 0; t < N; t += 8) {
#pragma unroll
    for (int s = 0; s < 8; ++s) {
      const int u = t + s;
      // accP=(zi,zf) partial, accQ=(zg,zo) partial; bias counted once per pair
      f32x2 accP, accQ;
      f32x2 zx = zr[s];
      if (p == 0) { accP = zx; accQ.x = 0.f; accQ.y = 0.f; }
      else        { accQ = zx; accP.x = 0.f; accP.y = 0.f; }
      { float2 v = pz[(u + 8) * 64]; zr[s].x = v.x; zr[s].y = v.y; }  // affine prefetch
      // ---- broadcast via 16 ds_bpermute (no write leg), packed into pairs ----
      unsigned hbits = __float_as_uint(h);
      f32x2 hk2[8];
#pragma unroll
      for (int q = 0; q < 8; ++q) {
        hk2[q].x = __uint_as_float((unsigned)__builtin_amdgcn_ds_bpermute(ba[2 * q],     (int)hbits));
        hk2[q].y = __uint_as_float((unsigned)__builtin_amdgcn_ds_bpermute(ba[2 * q + 1], (int)hbits));
      }
      // ---- 32 pk_fma over this lane's k-half ----
#pragma unroll
      for (int q = 0; q < 8; ++q) {
        PK_LO(accP, wP[2 * q],     hk2[q]);
        PK_LO(accQ, wQ[2 * q],     hk2[q]);
        PK_HI(accP, wP[2 * q + 1], hk2[q]);
        PK_HI(accQ, wQ[2 * q + 1], hk2[q]);
      }
      // ---- combine k-halves across the pair (DPP xor1; a+b bitwise commutative) ----
      float zi = accP.x + qperm<0xB1>(accP.x);
      float zf = accP.y + qperm<0xB1>(accP.y);
      float zg = accQ.x + qperm<0xB1>(accQ.x);
      float zo = accQ.y + qperm<0xB1>(accQ.y);
      // ---- full gate tail in every lane (h valid everywhere) ----
      float ig = __builtin_amdgcn_rcpf(1.f + exp2f(-zi));
      float fg = __builtin_amdgcn_rcpf(1.f + exp2f(-zf));
      float og = __builtin_amdgcn_rcpf(1.f + exp2f(-zo));
      float sg = __builtin_amdgcn_rcpf(1.f + exp2f(-zg));
      float gg = fmaf(2.f, sg, -1.f);       // tanh(zg)
      c = fmaf(fg, c, ig * gg);
      float r3 = __builtin_amdgcn_rcpf(1.f + exp2f(n2L * c));
      float tc = fmaf(2.f, r3, -1.f);       // tanh(c)
      h = og * tc;
    }
  }

  // c identical in lanes 2j,2j+1 — mask odd lanes, wave-reduce
  float v = (p == 0) ? fmaxf(c, 0.f) * fc1w[j] : 0.f;
#pragma unroll
  for (int off = 32; off; off >>= 1) v += __shfl_down(v, off, 64);
  if (l == 0) out[1] = v + fc1b[0];
}

extern "C" void kernel_launch(void* const* d_in, const int* in_sizes, int n_in,
                              void* d_out, int out_size, void* d_ws, size_t ws_size,
                              hipStream_t stream) {
  const float* x    = (const float*)d_in[0];
  const int*   ei   = (const int*)d_in[1];
  // d_in[2] edge_attr unused (edge_dim=None)
  const float* W1   = (const float*)d_in[3];
  const float* a1s  = (const float*)d_in[4];
  const float* a1d  = (const float*)d_in[5];
  const float* b1   = (const float*)d_in[6];
  const float* W2   = (const float*)d_in[7];
  const float* a2s  = (const float*)d_in[8];
  const float* a2d  = (const float*)d_in[9];
  const float* b2   = (const float*)d_in[10];
  const float* Wih  = (const float*)d_in[11];
  const float* Whh  = (const float*)d_in[12];
  const float* bih  = (const float*)d_in[13];
  const float* bhh  = (const float*)d_in[14];
  const float* fc1w = (const float*)d_in[15];
  const float* fc1b = (const float*)d_in[16];
  const float* f2w1 = (const float*)d_in[17];
  const float* f2b1 = (const float*)d_in[18];
  const float* f2w2 = (const float*)d_in[19];
  const float* f2b2 = (const float*)d_in[20];

  const int N  = in_sizes[0] / IN_F;   // 20000
  const int E  = in_sizes[1] / 2;      // 640000
  const int EP = E + N;                // 660000 (with self-loops)

  float* ws = (float*)d_ws;
  float*    out1  = ws + OFF_OUT1;
  float*    out2  = ws + OFF_OUT2;
  float*    d1    = ws + OFF_D1;
  float*    d2    = ws + OFF_D2;
  float*    sum   = ws + OFF_SUM;
  unsigned* m1    = (unsigned*)(ws + OFF_M1);
  unsigned* m2    = (unsigned*)(ws + OFF_M2);
  float*    h1    = ws + OFF_H1;
  float*    h2    = ws + OFF_H2;
  float*    es1   = ws + OFF_ES1;
  float*    ed1   = ws + OFF_ED1;
  float*    es2   = ws + OFF_ES2;
  float*    ed2   = ws + OFF_ED2;
  float*    ebuf  = ws + OFF_EBUF;
  float*    Zx    = ws + OFF_ZX;

  hipMemsetAsync(d_ws, 0, (size_t)ZERO_FLOATS * 4, stream);
  k_initm<<<(N + 255) / 256, 256, 0, stream>>>(m1, m2, N);

  // ---- GAT layer 1 ----
  k_gemm1<<<N, 64, 0, stream>>>(x, W1, a1s, a1d, h1, es1, ed1);
  int eb = (EP + 255) / 256;
  k_emax<<<eb, 256, 0, stream>>>(ei, es1, ed1, ebuf, m1, E, EP);
  k_ep<<<eb, 256, 0, stream>>>(ei, ebuf, m1, d1, E, EP);
  k_aggr<64><<<((size_t)EP * 64 + 255) / 256, 256, 0, stream>>>(ei, ebuf, d1, h1, out1, E, EP);

  // ---- GAT layer 2 ----
  k_gemm2<<<(N + 1) / 2, 64, 0, stream>>>(out1, b1, W2, a2s, a2d, h2, es2, ed2, N);
  k_emax<<<eb, 256, 0, stream>>>(ei, es2, ed2, ebuf, m2, E, EP);
  k_ep<<<eb, 256, 0, stream>>>(ei, ebuf, m2, d2, E, EP);
  k_aggr<32><<<((size_t)EP * 32 + 255) / 256, 256, 0, stream>>>(ei, ebuf, d2, h2, out2, E, EP);

  // ---- LSTM input projection + mean pool + heads ----
  k_zx<<<N, 128, 0, stream>>>(out2, b2, Wih, bih, bhh, Zx);
  k_mean<<<64, 256, 0, stream>>>(out2, b2, sum, N);
  k_head<<<1, 64, 0, stream>>>(sum, f2w1, f2b1, f2w2, f2b2, (float*)d_out, 1.f / (float)N);
  k_lstm<<<1, 64, 0, stream>>>(Zx, Whh, fc1w, fc1b, (float*)d_out, N);
}

// Round 11
// 5202.847 us; speedup vs baseline: 1.8402x; 1.8402x over previous
//
#include <hip/hip_runtime.h>

#define IN_F 128
#define HID_F 64
#define OUT_F 32
#define ENC_NEG_INF 0x007FFFFFu
#define LOG2E 1.44269504088896340736f

typedef float f32x2 __attribute__((ext_vector_type(2)));

// packed dual-FMA (proven r8): acc.lo += w.lo*h.lo, acc.hi += w.hi*h.lo  (broadcast lo)
#define PK_LO(acc, w, hs) \
  asm("v_pk_fma_f32 %0, %1, %2, %0 op_sel_hi:[1,0,1]" : "+v"(acc) : "v"(w), "v"(hs))
// acc.lo += w.lo*h.hi, acc.hi += w.hi*h.hi  (broadcast hi)
#define PK_HI(acc, w, hs) \
  asm("v_pk_fma_f32 %0, %1, %2, %0 op_sel:[0,1,0]" : "+v"(acc) : "v"(w), "v"(hs))

// ---------------- workspace layout (float offsets) ----------------
#define OFF_OUT1   0
#define OFF_OUT2   1280000
#define OFF_D1     1920000
#define OFF_D2     1940000
#define OFF_SUM    1960000
#define ZERO_FLOATS 1960064
#define OFF_M1     1960064
#define OFF_M2     1980064
#define OFF_H1     2000064
#define OFF_H2     3280064
#define OFF_ES1    3920064
#define OFF_ED1    3940064
#define OFF_ES2    3960064
#define OFF_ED2    3980064
#define OFF_EBUF   4000064
#define OFF_ZX     4660064    // 20000*128 + 1024 pad  LSTM input projection (PACKED+SCALED)

__device__ __forceinline__ unsigned enc_f(float f) {
  unsigned b = __float_as_uint(f);
  return (b & 0x80000000u) ? ~b : (b | 0x80000000u);
}
__device__ __forceinline__ float dec_f(unsigned u) {
  unsigned b = (u & 0x80000000u) ? (u & 0x7FFFFFFFu) : ~u;
  return __uint_as_float(b);
}

// DPP quad_perm cross-lane (pure VALU): 0xB1 = swap within lane pairs (xor1)
template <int CTRL>
__device__ __forceinline__ float qperm(float x) {
  return __uint_as_float((unsigned)__builtin_amdgcn_update_dpp(
      0, (int)__float_as_uint(x), CTRL, 0xF, 0xF, true));
}

__global__ void k_initm(unsigned* __restrict__ m1, unsigned* __restrict__ m2, int n) {
  int i = blockIdx.x * blockDim.x + threadIdx.x;
  if (i < n) { m1[i] = ENC_NEG_INF; m2[i] = ENC_NEG_INF; }
}

// h1 = x @ W1 ; es1 = h1 . a_src ; ed1 = h1 . a_dst   (one wave per node)
__global__ void k_gemm1(const float* __restrict__ x, const float* __restrict__ W1,
                        const float* __restrict__ a_src, const float* __restrict__ a_dst,
                        float* __restrict__ h1, float* __restrict__ es, float* __restrict__ ed) {
  int n = blockIdx.x;
  int f = threadIdx.x;           // 0..63
  const float* xr = x + n * IN_F;
  float acc = 0.f;
#pragma unroll 8
  for (int k = 0; k < IN_F; ++k) acc = fmaf(xr[k], W1[k * HID_F + f], acc);
  h1[n * HID_F + f] = acc;
  float s = acc * a_src[f];
  float d = acc * a_dst[f];
#pragma unroll
  for (int off = 32; off; off >>= 1) {
    s += __shfl_down(s, off, 64);
    d += __shfl_down(d, off, 64);
  }
  if (f == 0) { es[n] = s; ed[n] = d; }
}

__global__ void k_emax(const int* __restrict__ ei, const float* __restrict__ es,
                       const float* __restrict__ ed, float* __restrict__ ebuf,
                       unsigned* __restrict__ menc, int E, int EP) {
  int i = blockIdx.x * blockDim.x + threadIdx.x;
  if (i >= EP) return;
  int src, dst;
  if (i < E) { src = ei[i]; dst = ei[E + i]; } else { src = dst = i - E; }
  float e = es[src] + ed[dst];
  e = (e >= 0.f) ? e : 0.2f * e;
  ebuf[i] = e;
  atomicMax(&menc[dst], enc_f(e));
}

__global__ void k_ep(const int* __restrict__ ei, float* __restrict__ ebuf,
                     const unsigned* __restrict__ menc, float* __restrict__ denom,
                     int E, int EP) {
  int i = blockIdx.x * blockDim.x + threadIdx.x;
  if (i >= EP) return;
  int dst = (i < E) ? ei[E + i] : (i - E);
  float p = __expf(ebuf[i] - dec_f(menc[dst]));
  ebuf[i] = p;
  atomicAdd(&denom[dst], p);
}

template <int F>
__global__ void k_aggr(const int* __restrict__ ei, const float* __restrict__ ebuf,
                       const float* __restrict__ denom, const float* __restrict__ h,
                       float* __restrict__ out, int E, int EP) {
  int gt = blockIdx.x * blockDim.x + threadIdx.x;
  int lane = gt % F;
  int e = gt / F;
  if (e >= EP) return;
  int src, dst;
  if (e < E) { src = ei[e]; dst = ei[E + e]; } else { src = dst = e - E; }
  float alpha = ebuf[e] / denom[dst];
  atomicAdd(&out[dst * F + lane], alpha * h[src * F + lane]);
}

__global__ void k_gemm2(const float* __restrict__ out1, const float* __restrict__ b1,
                        const float* __restrict__ W2, const float* __restrict__ a_src,
                        const float* __restrict__ a_dst, float* __restrict__ h2,
                        float* __restrict__ es, float* __restrict__ ed, int N) {
  int lane = threadIdx.x;
  int f = lane & 31;
  int n = blockIdx.x * 2 + (lane >> 5);
  if (n >= N) return;
  const float* r = out1 + n * HID_F;
  float acc = 0.f;
#pragma unroll 8
  for (int k = 0; k < HID_F; ++k) {
    float v = r[k] + b1[k];
    v = v > 0.f ? v : 0.f;
    acc = fmaf(v, W2[k * OUT_F + f], acc);
  }
  h2[n * OUT_F + f] = acc;
  float s = acc * a_src[f];
  float d = acc * a_dst[f];
#pragma unroll
  for (int off = 16; off; off >>= 1) {
    s += __shfl_down(s, off, 32);
    d += __shfl_down(d, off, 32);
  }
  if (f == 0) { es[n] = s; ed[n] = d; }
}

// Zx packed+scaled (r8 layout): row r (gate-major: i=0..31,f=..63,g=..95,o=..127)
//   pos = (r&31)*4 + ((r>>5)&1)*2 + (r>>6)
// LSTM lane l=2j+p reads float2 at t*128 + l*2 : .x = gate p (i/f), .y = gate 2+p (g/o)
// rows i,f,o premultiplied by log2(e); row g by 2*log2(e)  (exp2-form gates)
__global__ void k_zx(const float* __restrict__ out2, const float* __restrict__ b2,
                     const float* __restrict__ Wih, const float* __restrict__ bih,
                     const float* __restrict__ bhh, float* __restrict__ Zx) {
  int r = threadIdx.x;   // 0..127
  int t = blockIdx.x;
  const float* xr = out2 + t * OUT_F;
  float acc = bih[r] + bhh[r];
#pragma unroll
  for (int k = 0; k < OUT_F; ++k) acc = fmaf(xr[k] + b2[k], Wih[r * OUT_F + k], acc);
  float scl = (r >= 64 && r < 96) ? 2.f * LOG2E : LOG2E;   // g-rows get 2L
  int pos = ((r & 31) << 2) | (((r >> 5) & 1) << 1) | (r >> 6);
  Zx[t * 128 + pos] = acc * scl;
}

__global__ void k_mean(const float* __restrict__ out2, const float* __restrict__ b2,
                       float* __restrict__ sum, int N) {
  int k = threadIdx.x & 31;
  int row = threadIdx.x >> 5;   // 0..7
  float acc = 0.f;
  for (int n = blockIdx.x * 8 + row; n < N; n += gridDim.x * 8)
    acc += out2[n * OUT_F + k] + b2[k];
  __shared__ float s[256];
  s[threadIdx.x] = acc;
  __syncthreads();
  if (threadIdx.x < 32) {
    float tot = 0.f;
#pragma unroll
    for (int j = 0; j < 8; ++j) tot += s[j * 32 + k];
    atomicAdd(&sum[k], tot);
  }
}

__global__ void k_head(const float* __restrict__ sum, const float* __restrict__ w1,
                       const float* __restrict__ bb1, const float* __restrict__ w2,
                       const float* __restrict__ bb2, float* __restrict__ out, float invN) {
  if (threadIdx.x == 0 && blockIdx.x == 0) {
    float xc[32];
#pragma unroll
    for (int k = 0; k < 32; ++k) xc[k] = sum[k] * invN;
    float t2 = bb2[0];
    for (int j = 0; j < 16; ++j) {
      float a = bb1[j];
#pragma unroll
      for (int k = 0; k < 32; ++k) a = fmaf(w1[j * 32 + k], xc[k], a);
      a = a > 0.f ? a : 0.f;
      t2 = fmaf(w2[j], a, t2);
    }
    out[0] = 1.f / (1.f + __expf(-t2));
  }
}

// sequential LSTM round-11: ONE wave, zero barriers. HYBRID split broadcast:
//   EARLY k-half (k=0..15): 16 v_readlane -> SGPRs, feeding scalar v_fmac chains
//     immediately (issue-bound, no latency).
//   LATE k-half (k=16..31): 8 uniform ds_read_b64 from double-buffered LDS,
//     issued at step start -> ~150cy latency hides under readlanes+early FMAs;
//     consumed by 16 v_pk_fma (r8 PK macros).
// Summation grouping identical to r7 (a0 = zx + k<16 chain; a1 = k>=16 chain;
// z = a0+a1) — both halves bit-match previously passing kernels.
// Tail: r8 lane-split form (3 exp2 + 3 rcp, qperm exchange); h valid on even
// lanes; h published to hb[u&1] (odd lanes -> dummy half; 2 lanes/bank = free).
// In-order DS pipe makes write(t-1)->read(t) safe without barriers.
__global__ void __launch_bounds__(64, 1) k_lstm(
    const float* __restrict__ Zx, const float* __restrict__ Whh,
    const float* __restrict__ fc1w, const float* __restrict__ fc1b,
    float* __restrict__ out, int N) {
  const int l = threadIdx.x;     // 0..63
  const int j = l >> 1;
  const int p = l & 1;
  const int rowA = p * 32 + j;         // i_j (p=0) or f_j (p=1)
  const int rowB = (2 + p) * 32 + j;   // g_j (p=0) or o_j (p=1)
  const float sclA = LOG2E;
  const float sclB = p ? LOG2E : 2.f * LOG2E;

  f32x2 w2[32];   // w2[k] = (wA[k], wB[k])
#pragma unroll
  for (int k = 0; k < 32; ++k) {
    f32x2 w;
    w.x = Whh[rowA * 32 + k] * sclA;
    w.y = Whh[rowB * 32 + k] * sclB;
    w2[k] = w;
  }

  __shared__ float hb[2][64];    // [buf][0:32)=h, [32:64)=dummy (odd lanes)
  hb[1][l] = 0.f;                // h(-1) in buf[1]; same-wave in-order DS pipe

  const float2* pz = (const float2*)Zx + l;   // lane's float2 column; step stride 64
  f32x2 zr[8];
#pragma unroll
  for (int s = 0; s < 8; ++s) { float2 v = pz[s * 64]; zr[s].x = v.x; zr[s].y = v.y; }

  const float n2L = -2.f * LOG2E;
  float h = 0.f, c = 0.f;
  // N divisible by 8 (N=20000)
  for (int t = 0; t < N; t += 8) {
#pragma unroll
    for (int s = 0; s < 8; ++s) {
      const int u = t + s;
      // ---- LATE half: issue 8 uniform ds_read_b64 (pairs h16..h31) EARLY ----
      const f32x2* hbr = (const f32x2*)hb[(u + 1) & 1];
      f32x2 hk2[8];
#pragma unroll
      for (int q = 0; q < 8; ++q) hk2[q] = hbr[8 + q];
      // ---- Zx prefetch (affine; pad covers tail) ----
      f32x2 zx = zr[s];
      { float2 v = pz[(u + 8) * 64]; zr[s].x = v.x; zr[s].y = v.y; }
      // ---- EARLY half: 16 readlanes (h_k in even lane 2k) -> scalar FMA chains ----
      unsigned hbits = __float_as_uint(h);
      float hk[16];
#pragma unroll
      for (int k = 0; k < 16; ++k)
        hk[k] = __uint_as_float(__builtin_amdgcn_readlane(hbits, 2 * k));
      float a0 = zx.x, b0 = zx.y;
#pragma unroll
      for (int k = 0; k < 16; ++k) {
        a0 = fmaf(w2[k].x, hk[k], a0);       // v_fmac v, s, v
        b0 = fmaf(w2[k].y, hk[k], b0);
      }
      // ---- LATE half: 16 pk_fma on (zA,zB) pair accumulator ----
      f32x2 accP; accP.x = 0.f; accP.y = 0.f;
#pragma unroll
      for (int q = 0; q < 8; ++q) {
        PK_LO(accP, w2[16 + 2 * q],     hk2[q]);
        PK_HI(accP, w2[16 + 2 * q + 1], hk2[q]);
      }
      float zA = a0 + accP.x;
      float zB = b0 + accP.y;
      // even: zA=L*zi, zB=2L*zg ; odd: zA=L*zf, zB=L*zo   (r8 tail verbatim)
      float sA = __builtin_amdgcn_rcpf(1.f + exp2f(-zA));  // even: ig ; odd: fg
      float sB = __builtin_amdgcn_rcpf(1.f + exp2f(-zB));  // even: sig(2zg) ; odd: og
      float fgx = qperm<0xB1>(sA);          // even lane receives fg
      float ogx = qperm<0xB1>(sB);          // even lane receives og
      float gg = fmaf(2.f, sB, -1.f);       // even: tanh(zg)
      c = fmaf(fgx, c, sA * gg);            // valid on even lanes only
      float r3 = __builtin_amdgcn_rcpf(1.f + exp2f(n2L * c));
      float tc = fmaf(2.f, r3, -1.f);       // tanh(c)
      h = ogx * tc;                         // valid on even lanes only
      hb[u & 1][p * 32 + j] = h;            // publish h(u); odd lanes -> dummy
    }
  }

  // c valid in even lanes; mask odd lanes, wave-reduce
  float v = (p == 0) ? fmaxf(c, 0.f) * fc1w[j] : 0.f;
#pragma unroll
  for (int off = 32; off; off >>= 1) v += __shfl_down(v, off, 64);
  if (l == 0) out[1] = v + fc1b[0];
}

extern "C" void kernel_launch(void* const* d_in, const int* in_sizes, int n_in,
                              void* d_out, int out_size, void* d_ws, size_t ws_size,
                              hipStream_t stream) {
  const float* x    = (const float*)d_in[0];
  const int*   ei   = (const int*)d_in[1];
  // d_in[2] edge_attr unused (edge_dim=None)
  const float* W1   = (const float*)d_in[3];
  const float* a1s  = (const float*)d_in[4];
  const float* a1d  = (const float*)d_in[5];
  const float* b1   = (const float*)d_in[6];
  const float* W2   = (const float*)d_in[7];
  const float* a2s  = (const float*)d_in[8];
  const float* a2d  = (const float*)d_in[9];
  const float* b2   = (const float*)d_in[10];
  const float* Wih  = (const float*)d_in[11];
  const float* Whh  = (const float*)d_in[12];
  const float* bih  = (const float*)d_in[13];
  const float* bhh  = (const float*)d_in[14];
  const float* fc1w = (const float*)d_in[15];
  const float* fc1b = (const float*)d_in[16];
  const float* f2w1 = (const float*)d_in[17];
  const float* f2b1 = (const float*)d_in[18];
  const float* f2w2 = (const float*)d_in[19];
  const float* f2b2 = (const float*)d_in[20];

  const int N  = in_sizes[0] / IN_F;   // 20000
  const int E  = in_sizes[1] / 2;      // 640000
  const int EP = E + N;                // 660000 (with self-loops)

  float* ws = (float*)d_ws;
  float*    out1  = ws + OFF_OUT1;
  float*    out2  = ws + OFF_OUT2;
  float*    d1    = ws + OFF_D1;
  float*    d2    = ws + OFF_D2;
  float*    sum   = ws + OFF_SUM;
  unsigned* m1    = (unsigned*)(ws + OFF_M1);
  unsigned* m2    = (unsigned*)(ws + OFF_M2);
  float*    h1    = ws + OFF_H1;
  float*    h2    = ws + OFF_H2;
  float*    es1   = ws + OFF_ES1;
  float*    ed1   = ws + OFF_ED1;
  float*    es2   = ws + OFF_ES2;
  float*    ed2   = ws + OFF_ED2;
  float*    ebuf  = ws + OFF_EBUF;
  float*    Zx    = ws + OFF_ZX;

  hipMemsetAsync(d_ws, 0, (size_t)ZERO_FLOATS * 4, stream);
  k_initm<<<(N + 255) / 256, 256, 0, stream>>>(m1, m2, N);

  // ---- GAT layer 1 ----
  k_gemm1<<<N, 64, 0, stream>>>(x, W1, a1s, a1d, h1, es1, ed1);
  int eb = (EP + 255) / 256;
  k_emax<<<eb, 256, 0, stream>>>(ei, es1, ed1, ebuf, m1, E, EP);
  k_ep<<<eb, 256, 0, stream>>>(ei, ebuf, m1, d1, E, EP);
  k_aggr<64><<<((size_t)EP * 64 + 255) / 256, 256, 0, stream>>>(ei, ebuf, d1, h1, out1, E, EP);

  // ---- GAT layer 2 ----
  k_gemm2<<<(N + 1) / 2, 64, 0, stream>>>(out1, b1, W2, a2s, a2d, h2, es2, ed2, N);
  k_emax<<<eb, 256, 0, stream>>>(ei, es2, ed2, ebuf, m2, E, EP);
  k_ep<<<eb, 256, 0, stream>>>(ei, ebuf, m2, d2, E, EP);
  k_aggr<32><<<((size_t)EP * 32 + 255) / 256, 256, 0, stream>>>(ei, ebuf, d2, h2, out2, E, EP);

  // ---- LSTM input projection + mean pool + heads ----
  k_zx<<<N, 128, 0, stream>>>(out2, b2, Wih, bih, bhh, Zx);
  k_mean<<<64, 256, 0, stream>>>(out2, b2, sum, N);
  k_head<<<1, 64, 0, stream>>>(sum, f2w1, f2b1, f2w2, f2b2, (float*)d_out, 1.f / (float)N);
  k_lstm<<<1, 64, 0, stream>>>(Zx, Whh, fc1w, fc1b, (float*)d_out, N);
}